// Round 11
// baseline (331.559 us; speedup 1.0000x reference)
//
#include <hip/hip_runtime.h>

#define NNODES 16384
#define EDGES  262144
#define DH     128
#define NH     8
#define CH     16
#define NL     6
#define SEQ    128
#define NNPG   64

#define PBLK   768                 // prologue grid: 3 blocks/CU
#define PTHR   (PBLK * 256)
#define PWAV   (PBLK * 4)

typedef short bf16x8 __attribute__((ext_vector_type(8)));
typedef float f32x4 __attribute__((ext_vector_type(4)));
typedef float f32x2 __attribute__((ext_vector_type(2)));

static __device__ __forceinline__ unsigned short f2bf(float f) {
  unsigned u = __float_as_uint(f);
  u += 0x7FFFu + ((u >> 16) & 1u);   // round-to-nearest-even
  return (unsigned short)(u >> 16);
}
static __device__ __forceinline__ float bfl(unsigned u) { return __uint_as_float(u << 16); }
static __device__ __forceinline__ float bfh(unsigned u) { return __uint_as_float(u & 0xffff0000u); }
static __device__ __forceinline__ f32x2 mk2(float x, float y) { f32x2 t; t[0] = x; t[1] = y; return t; }

// ---------------- fused prologue: CSR scatter | weight convert | input proj ----
__global__ __launch_bounds__(256) void k_pro(const int* __restrict__ ei,
    int* __restrict__ cnt, int* __restrict__ csr_pad,
    const float* __restrict__ Wq, const float* __restrict__ Wk,
    const float* __restrict__ Wv, const float* __restrict__ Ws,
    unsigned short* __restrict__ Wf,
    const float* __restrict__ x, const float* __restrict__ Win,
    const float* __restrict__ bin, const float* __restrict__ pe,
    float* __restrict__ h, unsigned short* __restrict__ hb) {
  const int tid = threadIdx.x;
  const int lane = tid & 63, wid = tid >> 6;
  const int gtid = blockIdx.x * 256 + tid;
  const int gw = blockIdx.x * 4 + wid;

  // direct-scatter CSR (cnt pre-zeroed by memset); cnt becomes degree table
  for (int e = gtid; e < EDGES; e += PTHR) {
    const int d = ei[EDGES + e];
    const int s = ei[e];
    const int slot = atomicAdd(&cnt[d], 1);
    if (slot < 64) csr_pad[d * 64 + (slot & 7) * 8 + (slot >> 3)] = s;
  }

  // weight convert+swizzle: one 16x32 tile per wave, exactly NL*128 = 768 waves
  if (gw < NL * 128) {
    const int layer = gw >> 7, rem = gw & 127;
    const int mat = rem >> 5, tile = rem & 31;
    const int nt = tile >> 2, kt = tile & 3;
    const float* W = ((mat == 0) ? Wq : (mat == 1) ? Wk : (mat == 2) ? Wv : Ws)
                     + layer * DH * DH;
    const int nn = nt * 16 + (lane & 15);
    const int k0 = kt * 32 + (lane >> 4) * 8;
    unsigned pk[4];
#pragma unroll
    for (int jj = 0; jj < 4; ++jj) {
      const unsigned lo = f2bf(W[(k0 + 2 * jj) * DH + nn]);
      const unsigned hi = f2bf(W[(k0 + 2 * jj + 1) * DH + nn]);
      pk[jj] = lo | (hi << 16);
    }
    uint4 o = {pk[0], pk[1], pk[2], pk[3]};
    *(uint4*)&Wf[(((layer * 4 + mat) * 32 + tile) * 64 + lane) * 8] = o;
  }

  // input proj: wave per node, lane owns 2 dims
  for (int n = gw; n < NNODES; n += PWAV) {
    const int d0 = lane * 2;
    float xs[9];
#pragma unroll
    for (int f = 0; f < 9; ++f) xs[f] = x[n * 9 + f];
    float a0 = bin[d0], a1 = bin[d0 + 1];
#pragma unroll
    for (int f = 0; f < 9; ++f) {
      const float2 w = *(const float2*)&Win[f * DH + d0];
      a0 = fmaf(xs[f], w.x, a0);
      a1 = fmaf(xs[f], w.y, a1);
    }
    const float2 pev = *(const float2*)&pe[((n / NNPG) % SEQ) * DH + d0];
    const float v0 = a0 + pev.x, v1 = a1 + pev.y;
    float2 hv = {v0, v1};
    *(float2*)&h[n * DH + d0] = hv;
    *(unsigned*)&hb[n * DH + d0] = (unsigned)f2bf(v0) | ((unsigned)f2bf(v1) << 16);
  }
}

// ---------------- layer-0 Q/K/V/skip GEMM (A from hb via swizzled LDS) --------
__global__ __launch_bounds__(512, 2) void k_gemm(const unsigned short* __restrict__ hb,
    const unsigned short* __restrict__ Wf,
    const float* __restrict__ bq, const float* __restrict__ bk,
    const float* __restrict__ bv, const float* __restrict__ bs,
    unsigned short* __restrict__ qb, unsigned char* __restrict__ kv8,
    float* __restrict__ xr) {
  __shared__ uint4 As4[512];                   // 32 rows x 256B, swizzled
  const int mt = blockIdx.x;
  const int wv = threadIdx.x >> 6, lane = threadIdx.x & 63;
  {
    const int t = threadIdx.x;
    const int row = t >> 4, cb = t & 15;
    As4[t] = *(const uint4*)&hb[(mt * 32 + row) * DH + ((cb ^ (row & 7)) * 8)];
  }
  __syncthreads();

  const int cg = wv;                           // col group 0..7 (64 cols each)
  const int mat = cg >> 1, nbase = (cg & 1) * 64;
  const unsigned short* Wm = Wf + mat * 16384;
  const float* bias = (mat == 0) ? bq : (mat == 1) ? bk : (mat == 2) ? bv : bs;
  const int m0 = lane & 15, quad = lane >> 4;
  const int nt0 = (cg & 1) * 4;
  const char* Asb = (const char*)As4;

  const f32x4 z = {0.f, 0.f, 0.f, 0.f};
  f32x4 acc[2][4] = {{z, z, z, z}, {z, z, z, z}};
#pragma unroll
  for (int kt = 0; kt < 4; ++kt) {
    const int cbr = kt * 4 + quad;
    const bf16x8 a0 = *(const bf16x8*)(Asb + m0 * 256 + ((cbr ^ (m0 & 7)) * 16));
    const bf16x8 a1 = *(const bf16x8*)(Asb + (16 + m0) * 256 + ((cbr ^ (m0 & 7)) * 16));
#pragma unroll
    for (int j = 0; j < 4; ++j) {
      const bf16x8 b = *(const bf16x8*)&Wm[(((nt0 + j) * 4 + kt) * 64 + lane) * 8];
      acc[0][j] = __builtin_amdgcn_mfma_f32_16x16x32_bf16(a0, b, acc[0][j], 0, 0, 0);
      acc[1][j] = __builtin_amdgcn_mfma_f32_16x16x32_bf16(a1, b, acc[1][j], 0, 0, 0);
    }
  }
  const int kvoff = (mat == 1) ? 0 : 16;
#pragma unroll
  for (int half = 0; half < 2; ++half) {
#pragma unroll
    for (int j = 0; j < 4; ++j) {
      const int col = nbase + j * 16 + m0;
      const float bvv = bias[col];
#pragma unroll
      for (int r = 0; r < 4; ++r) {
        const float val = acc[half][j][r] + bvv;
        const int row = mt * 32 + half * 16 + quad * 4 + r;
        if (mat == 0) {
          qb[row * DH + col] = f2bf(val);
        } else if (mat == 3) {
          xr[row * DH + col] = val;
        } else {
          const float nbv = __shfl_xor(val, 1);
          if ((lane & 1) == 0) {
            const int pk = __builtin_amdgcn_cvt_pk_fp8_f32(val, nbv, 0, false);
            const int head = col >> 4, dim = col & 15;
            *(unsigned short*)&kv8[row * 256 + head * 32 + kvoff + dim] =
                (unsigned short)pk;
          }
        }
      }
    }
  }
}

// ---------------- attention helpers ----------------
__device__ __forceinline__ void decode16bf2(const uint4 a, const uint4 b, f32x2* r) {
  r[0] = mk2(bfl(a.x), bfh(a.x)); r[1] = mk2(bfl(a.y), bfh(a.y));
  r[2] = mk2(bfl(a.z), bfh(a.z)); r[3] = mk2(bfl(a.w), bfh(a.w));
  r[4] = mk2(bfl(b.x), bfh(b.x)); r[5] = mk2(bfl(b.y), bfh(b.y));
  r[6] = mk2(bfl(b.z), bfh(b.z)); r[7] = mk2(bfl(b.w), bfh(b.w));
}

__device__ __forceinline__ void decode8x2(const uint4 u, f32x2* r) {
  r[0] = __builtin_amdgcn_cvt_pk_f32_fp8(u.x, false);
  r[1] = __builtin_amdgcn_cvt_pk_f32_fp8(u.x, true);
  r[2] = __builtin_amdgcn_cvt_pk_f32_fp8(u.y, false);
  r[3] = __builtin_amdgcn_cvt_pk_f32_fp8(u.y, true);
  r[4] = __builtin_amdgcn_cvt_pk_f32_fp8(u.z, false);
  r[5] = __builtin_amdgcn_cvt_pk_f32_fp8(u.z, true);
  r[6] = __builtin_amdgcn_cvt_pk_f32_fp8(u.w, false);
  r[7] = __builtin_amdgcn_cvt_pk_f32_fp8(u.w, true);
}

__device__ __forceinline__ void edge_acc2(const uint4 ku, const uint4 vu, bool valid,
    const f32x2* __restrict__ q2, f32x2* __restrict__ a2, float& denom) {
  f32x2 kr[8];
  decode8x2(ku, kr);
  f32x2 d2 = mk2(0.f, 0.f);
#pragma unroll
  for (int c = 0; c < 8; ++c) d2 = d2 + q2[c] * kr[c];
  const float dot = d2[0] + d2[1];
  const float ex = valid ? __expf(dot * 0.25f) : 0.f;
  denom += ex;
  f32x2 vr[8];
  decode8x2(vu, vr);
  const f32x2 e2 = mk2(ex, ex);
#pragma unroll
  for (int c = 0; c < 8; ++c) a2[c] = a2[c] + e2 * vr[c];
}

// ---------------- fused layer: attn(l) + epi + [gemm(l+1) | final MLP] --------
// Round-10 structure + depth-2 gather pipeline: node t+1's K/V gathers issue
// during node t's compute (double-buffered kf/vf, parity via manually
// instantiated iterations -> static array refs, no runtime indexing).
// iv/deg control kept depth-2; q/xr/h stream ctl depth-1. FP order unchanged.
template <bool LAST>
__global__ __launch_bounds__(512, 2) void k_layer(
    const unsigned short* __restrict__ qb_i, const unsigned char* __restrict__ kv8_i,
    const int* __restrict__ degv, const int* __restrict__ csr_pad,
    float* __restrict__ h, const float* __restrict__ xr_i,
    const float* __restrict__ Wb, const float* __restrict__ bb,
    const float* __restrict__ ln_g, const float* __restrict__ ln_b,
    const unsigned short* __restrict__ Wfn, const float* __restrict__ bqn,
    const float* __restrict__ bkn, const float* __restrict__ bvn,
    const float* __restrict__ bsn,
    unsigned short* __restrict__ qb_o, unsigned char* __restrict__ kv8_o,
    float* __restrict__ xr_o,
    const float* __restrict__ Wo1, const float* __restrict__ bo1,
    const float* __restrict__ Wo2, const float* __restrict__ bo2,
    float* __restrict__ out) {
  __shared__ float hsf[32][DH];   // 16KB; !LAST: first 8KB = swizzled bf16 A-tile
  const int wv = threadIdx.x >> 6, lane = threadIdx.x & 63;
  const int nb = blockIdx.x * 32;
  const int es = lane >> 3, hd = lane & 7;   // 8 edge-slots x 8 heads
  const int d0 = hd * CH + es * 2;
  // loop-invariant epilogue operands
  const float2 lw0 = *(const float2*)&Wb[d0];
  const float2 lw1 = *(const float2*)&Wb[DH + d0];
  const float2 lw2 = *(const float2*)&Wb[2 * DH + d0];
  const float2 lg = *(const float2*)&ln_g[d0];
  const float2 lb = *(const float2*)&ln_b[d0];
  const float bbv = bb[0];
  const int n0 = nb + wv * 4;

  // depth-2 gather control
  int4 iv0 = *(const int4*)&csr_pad[n0 * 64 + es * 8];
  int4 iv1 = *(const int4*)&csr_pad[(n0 + 1) * 64 + es * 8];
  int deg0 = degv[n0], deg1 = degv[n0 + 1];
  // depth-1 stream ctl (node 0)
  const uint4* qp0 = (const uint4*)&qb_i[n0 * DH + hd * CH];
  uint4 qa = qp0[0], qc = qp0[1];
  float2 xrv = *(const float2*)&xr_i[n0 * DH + d0];
  float2 hv = *(const float2*)&h[n0 * DH + d0];

  uint4 kfA[4], vfA[4], kfB[4], vfB[4];
  // prologue: gather node 0 -> A
  {
    int ntbg = (deg0 + 7) >> 3;
    if (ntbg > 4) ntbg = 4;
    const int idx[4] = {iv0.x, iv0.y, iv0.z, iv0.w};
#pragma unroll
    for (int t = 0; t < 4; ++t) {
      if (t < ntbg) {
        const bool v = (es + 8 * t) < deg0;
        const int s = v ? idx[t] : 0;
        const unsigned char* base = &kv8_i[s * 256 + hd * 32];
        kfA[t] = *(const uint4*)base;
        vfA[t] = *(const uint4*)(base + 16);
      }
    }
  }

  auto iter = [&](uint4 (&kfc)[4], uint4 (&vfc)[4],
                  uint4 (&kfn)[4], uint4 (&vfn)[4], int t4) {
    const int row = wv * 4 + t4;
    const int n = nb + row;
    // 1) issue node t4+1 gathers (iv1/deg1 resident a full iteration)
    if (t4 < 3) {
      int ntbg = (deg1 + 7) >> 3;
      if (ntbg > 4) ntbg = 4;
      const int idxn[4] = {iv1.x, iv1.y, iv1.z, iv1.w};
#pragma unroll
      for (int t = 0; t < 4; ++t) {
        if (t < ntbg) {
          const bool v = (es + 8 * t) < deg1;
          const int s = v ? idxn[t] : 0;
          const unsigned char* base = &kv8_i[s * 256 + hd * 32];
          kfn[t] = *(const uint4*)base;
          vfn[t] = *(const uint4*)(base + 16);
        }
      }
    }
    // 2) prefetch node t4+2 gather control
    int4 iv2 = iv1;
    int deg2 = deg1;
    if (t4 < 2) {
      iv2 = *(const int4*)&csr_pad[(n + 2) * 64 + es * 8];
      deg2 = degv[n + 2];
    }
    // 3) prefetch node t4+1 stream ctl
    uint4 qa_n = qa, qc_n = qc;
    float2 xr_n = xrv, hv_n = hv;
    if (t4 < 3) {
      const uint4* qp = (const uint4*)&qb_i[(n + 1) * DH + hd * CH];
      qa_n = qp[0];
      qc_n = qp[1];
      xr_n = *(const float2*)&xr_i[(n + 1) * DH + d0];
      hv_n = *(const float2*)&h[(n + 1) * DH + d0];
    }
    // 4) compute node t4 (FP order identical to round 10)
    int ntb = (deg0 + 7) >> 3;
    if (ntb > 8) ntb = 8;
    bool valv[4];
#pragma unroll
    for (int t = 0; t < 4; ++t) valv[t] = (es + 8 * t) < deg0;
    f32x2 q2[8];
    decode16bf2(qa, qc, q2);
    f32x2 a2[8];
#pragma unroll
    for (int c = 0; c < 8; ++c) a2[c] = mk2(0.f, 0.f);
    float denom = 0.f;
#pragma unroll
    for (int t = 0; t < 4; ++t) {
      if (t < ntb) edge_acc2(kfc[t], vfc[t], valv[t], q2, a2, denom);
    }
    for (int t = 4; t < ntb; ++t) {  // rare tail (deg > 32): slots 32..63
      const bool v = (es + 8 * t) < deg0;
      const int s = v ? csr_pad[n * 64 + es * 8 + t] : 0;
      const unsigned char* base = &kv8_i[s * 256 + hd * 32];
      const uint4 ku = *(const uint4*)base;
      const uint4 vu = *(const uint4*)(base + 16);
      edge_acc2(ku, vu, v, q2, a2, denom);
    }
#pragma unroll
    for (int off = 8; off <= 32; off <<= 1) denom += __shfl_xor(denom, off);
    // reduce-scatter across edge-slots; lane keeps only its own pair (c = es)
    const bool hi32 = (lane & 32) != 0;
    f32x2 r4[4];
#pragma unroll
    for (int c = 0; c < 4; ++c) {
      const f32x2 keep = hi32 ? a2[c + 4] : a2[c];
      const f32x2 send = hi32 ? a2[c] : a2[c + 4];
      const f32x2 rec = mk2(__shfl_xor(send[0], 32), __shfl_xor(send[1], 32));
      r4[c] = keep + rec;
    }
    const bool hi16 = (lane & 16) != 0;
    f32x2 r2[2];
#pragma unroll
    for (int c = 0; c < 2; ++c) {
      const f32x2 keep = hi16 ? r4[c + 2] : r4[c];
      const f32x2 send = hi16 ? r4[c] : r4[c + 2];
      const f32x2 rec = mk2(__shfl_xor(send[0], 16), __shfl_xor(send[1], 16));
      r2[c] = keep + rec;
    }
    const bool hi8 = (lane & 8) != 0;
    f32x2 rr;
    {
      const f32x2 keep = hi8 ? r2[1] : r2[0];
      const f32x2 send = hi8 ? r2[0] : r2[1];
      const f32x2 rec = mk2(__shfl_xor(send[0], 8), __shfl_xor(send[1], 8));
      rr = keep + rec;
    }
    const float inv = 1.f / (denom + 1e-16f);
    const float ax = rr[0] * inv, ay = rr[1] * inv;
    float p = ax * lw0.x + ay * lw0.y + xrv.x * lw1.x + xrv.y * lw1.y
            + (ax - xrv.x) * lw2.x + (ay - xrv.y) * lw2.y;
#pragma unroll
    for (int off = 1; off <= 32; off <<= 1) p += __shfl_xor(p, off);
    const float beta = 1.f / (1.f + __expf(-(p + bbv)));
    const float t0 = hv.x + beta * xrv.x + (1.f - beta) * ax;
    const float t1 = hv.y + beta * xrv.y + (1.f - beta) * ay;
    float sum = t0 + t1, sq = t0 * t0 + t1 * t1;
#pragma unroll
    for (int off = 1; off <= 32; off <<= 1) {
      sum += __shfl_xor(sum, off);
      sq  += __shfl_xor(sq, off);
    }
    const float mu = sum * (1.f / DH);
    const float rinv = rsqrtf(sq * (1.f / DH) - mu * mu + 1e-5f);
    const float2 o = {(t0 - mu) * rinv * lg.x + lb.x, (t1 - mu) * rinv * lg.y + lb.y};
    if constexpr (!LAST) {
      *(float2*)&h[n * DH + d0] = o;
      // next-layer A-tile: bf16 pair -> swizzled LDS (2-way banks = free)
      const int cb = 2 * hd + (es >> 2);     // linear 16B-block index of d0
      *(unsigned*)((char*)hsf + row * 256 + ((cb ^ (row & 7)) * 16) + (es & 3) * 4) =
          (unsigned)f2bf(o.x) | ((unsigned)f2bf(o.y) << 16);
    } else {
      hsf[row][d0] = o.x;
      hsf[row][d0 + 1] = o.y;
    }
    // 5) rotate control (compiler renames; statically unrolled call sites)
    iv0 = iv1; deg0 = deg1;
    iv1 = iv2; deg1 = deg2;
    qa = qa_n; qc = qc_n; xrv = xr_n; hv = hv_n;
  };
  // manual instantiation: static buffer parity, compile-time t4
  iter(kfA, vfA, kfB, vfB, 0);
  iter(kfB, vfB, kfA, vfA, 1);
  iter(kfA, vfA, kfB, vfB, 2);
  iter(kfB, vfB, kfA, vfA, 3);
  __syncthreads();

  if constexpr (!LAST) {
    // ---- gemm(l+1) for rows nb..nb+31, A from LDS
    const int cg = wv;
    const int mat = cg >> 1, nbase = (cg & 1) * 64;
    const unsigned short* Wm = Wfn + mat * 16384;
    const float* bias = (mat == 0) ? bqn : (mat == 1) ? bkn : (mat == 2) ? bvn : bsn;
    const int m0 = lane & 15, quad = lane >> 4;
    const int nt0 = (cg & 1) * 4;
    const char* Asb = (const char*)hsf;
    const f32x4 z = {0.f, 0.f, 0.f, 0.f};
    f32x4 acc[2][4] = {{z, z, z, z}, {z, z, z, z}};
#pragma unroll
    for (int kt = 0; kt < 4; ++kt) {
      const int cbr = kt * 4 + quad;
      const bf16x8 a0 = *(const bf16x8*)(Asb + m0 * 256 + ((cbr ^ (m0 & 7)) * 16));
      const bf16x8 a1 = *(const bf16x8*)(Asb + (16 + m0) * 256 + ((cbr ^ (m0 & 7)) * 16));
#pragma unroll
      for (int j = 0; j < 4; ++j) {
        const bf16x8 b = *(const bf16x8*)&Wm[(((nt0 + j) * 4 + kt) * 64 + lane) * 8];
        acc[0][j] = __builtin_amdgcn_mfma_f32_16x16x32_bf16(a0, b, acc[0][j], 0, 0, 0);
        acc[1][j] = __builtin_amdgcn_mfma_f32_16x16x32_bf16(a1, b, acc[1][j], 0, 0, 0);
      }
    }
    const int kvoff = (mat == 1) ? 0 : 16;
#pragma unroll
    for (int half = 0; half < 2; ++half) {
#pragma unroll
      for (int j = 0; j < 4; ++j) {
        const int col = nbase + j * 16 + m0;
        const float bvv = bias[col];
#pragma unroll
        for (int r = 0; r < 4; ++r) {
          const float val = acc[half][j][r] + bvv;
          const int row = nb + half * 16 + quad * 4 + r;
          if (mat == 0) {
            qb_o[row * DH + col] = f2bf(val);
          } else if (mat == 3) {
            xr_o[row * DH + col] = val;
          } else {
            const float nbv = __shfl_xor(val, 1);
            if ((lane & 1) == 0) {
              const int pk = __builtin_amdgcn_cvt_pk_fp8_f32(val, nbv, 0, false);
              const int head = col >> 4, dim = col & 15;
              *(unsigned short*)&kv8_o[row * 256 + head * 32 + kvoff + dim] =
                  (unsigned short)pk;
            }
          }
        }
      }
    }
  } else {
    // ---- final MLP: relu(h@Wo1+bo1)@Wo2+bo2; wave loops its 4 nodes
    for (int t4 = 0; t4 < 4; ++t4) {
      const int row = wv * 4 + t4;
      const int n = nb + row;
      float m = bo1[lane];
#pragma unroll 16
      for (int d = 0; d < DH; ++d) m = fmaf(hsf[row][d], Wo1[d * 64 + lane], m);
      m = fmaxf(m, 0.f);
      float o0 = m * Wo2[lane * 3 + 0];
      float o1 = m * Wo2[lane * 3 + 1];
      float o2 = m * Wo2[lane * 3 + 2];
#pragma unroll
      for (int off = 32; off; off >>= 1) {
        o0 += __shfl_xor(o0, off);
        o1 += __shfl_xor(o1, off);
        o2 += __shfl_xor(o2, off);
      }
      if (lane == 0) {
        out[n * 3 + 0] = o0 + bo2[0];
        out[n * 3 + 1] = o1 + bo2[1];
        out[n * 3 + 2] = o2 + bo2[2];
      }
    }
  }
}

extern "C" void kernel_launch(void* const* d_in, const int* in_sizes, int n_in,
                              void* d_out, int out_size, void* d_ws, size_t ws_size,
                              hipStream_t stream) {
  const float* x   = (const float*)d_in[0];
  const int*   ei  = (const int*)d_in[1];
  const float* pe  = (const float*)d_in[2];
  const float* Win = (const float*)d_in[3];
  const float* bin = (const float*)d_in[4];
  const float* Wq  = (const float*)d_in[5];
  const float* bq  = (const float*)d_in[6];
  const float* Wk  = (const float*)d_in[7];
  const float* bk  = (const float*)d_in[8];
  const float* Wv  = (const float*)d_in[9];
  const float* bv  = (const float*)d_in[10];
  const float* Wsk = (const float*)d_in[11];
  const float* bs  = (const float*)d_in[12];
  const float* Wb  = (const float*)d_in[13];
  const float* bb  = (const float*)d_in[14];
  const float* lng = (const float*)d_in[15];
  const float* lnb = (const float*)d_in[16];
  const float* Wo1 = (const float*)d_in[17];
  const float* bo1 = (const float*)d_in[18];
  const float* Wo2 = (const float*)d_in[19];
  const float* bo2 = (const float*)d_in[20];

  const size_t NU = (size_t)NNODES * DH;
  char* base = (char*)d_ws;
  float* h   = (float*)base;                  base += NU * 4;
  unsigned short* hb = (unsigned short*)base; base += NU * 2;
  unsigned short* Wf = (unsigned short*)base; base += (size_t)NL * 4 * 16384 * 2;
  int* cnt     = (int*)base;                  base += NNODES * 4;     // degree table
  int* csr_pad = (int*)base;                  base += (size_t)NNODES * 64 * 4;
  // ping-pong per-layer buffers (WAR-free fused gemm)
  float* xrA = (float*)base;                  base += NU * 4;
  float* xrB = (float*)base;                  base += NU * 4;
  unsigned short* qbA = (unsigned short*)base; base += NU * 2;
  unsigned short* qbB = (unsigned short*)base; base += NU * 2;
  unsigned char* kvA = (unsigned char*)base;  base += NU * 2;
  unsigned char* kvB = (unsigned char*)base;  base += NU * 2;

  (void)hipMemsetAsync(cnt, 0, NNODES * sizeof(int), stream);
  k_pro<<<PBLK, 256, 0, stream>>>(ei, cnt, csr_pad, Wq, Wk, Wv, Wsk, Wf,
                                  x, Win, bin, pe, h, hb);
  k_gemm<<<NNODES / 32, 512, 0, stream>>>(hb, Wf, bq, bk, bv, bs, qbA, kvA, xrA);
  for (int l = 0; l < NL - 1; ++l) {
    const bool even = (l & 1) == 0;
    k_layer<false><<<NNODES / 32, 512, 0, stream>>>(
        even ? qbA : qbB, even ? kvA : kvB, cnt, csr_pad, h, even ? xrA : xrB,
        Wb + l * 3 * DH, bb + l, lng + l * DH, lnb + l * DH,
        Wf + (size_t)(l + 1) * 4 * 16384,
        bq + (l + 1) * DH, bk + (l + 1) * DH, bv + (l + 1) * DH, bs + (l + 1) * DH,
        even ? qbB : qbA, even ? kvB : kvA, even ? xrB : xrA,
        Wo1, bo1, Wo2, bo2, (float*)d_out);
  }
  // l = 5 is odd -> reads B set
  k_layer<true><<<NNODES / 32, 512, 0, stream>>>(
      qbB, kvB, cnt, csr_pad, h, xrB,
      Wb + 5 * 3 * DH, bb + 5, lng + 5 * DH, lnb + 5 * DH,
      Wf, bq, bk, bv, bs, qbA, kvA, xrA,
      Wo1, bo1, Wo2, bo2, (float*)d_out);
}

// Round 13
// 315.893 us; speedup vs baseline: 1.0496x; 1.0496x over previous
//
#include <hip/hip_runtime.h>

#define NNODES 16384
#define EDGES  262144
#define DH     128
#define NH     8
#define CH     16
#define NL     6
#define SEQ    128
#define NNPG   64

#define PBLK   768                 // prologue grid: 3 blocks/CU
#define PTHR   (PBLK * 256)
#define PWAV   (PBLK * 4)

typedef short bf16x8 __attribute__((ext_vector_type(8)));
typedef float f32x4 __attribute__((ext_vector_type(4)));
typedef float f32x2 __attribute__((ext_vector_type(2)));

static __device__ __forceinline__ unsigned short f2bf(float f) {
  unsigned u = __float_as_uint(f);
  u += 0x7FFFu + ((u >> 16) & 1u);   // round-to-nearest-even
  return (unsigned short)(u >> 16);
}
static __device__ __forceinline__ float bfl(unsigned u) { return __uint_as_float(u << 16); }
static __device__ __forceinline__ float bfh(unsigned u) { return __uint_as_float(u & 0xffff0000u); }
static __device__ __forceinline__ f32x2 mk2(float x, float y) { f32x2 t; t[0] = x; t[1] = y; return t; }

// ---------------- fused prologue: CSR scatter | weight convert | input proj ----
__global__ __launch_bounds__(256) void k_pro(const int* __restrict__ ei,
    int* __restrict__ cnt, int* __restrict__ csr_pad,
    const float* __restrict__ Wq, const float* __restrict__ Wk,
    const float* __restrict__ Wv, const float* __restrict__ Ws,
    unsigned short* __restrict__ Wf,
    const float* __restrict__ x, const float* __restrict__ Win,
    const float* __restrict__ bin, const float* __restrict__ pe,
    float* __restrict__ h, unsigned short* __restrict__ hb) {
  const int tid = threadIdx.x;
  const int lane = tid & 63, wid = tid >> 6;
  const int gtid = blockIdx.x * 256 + tid;
  const int gw = blockIdx.x * 4 + wid;

  // direct-scatter CSR (cnt pre-zeroed by memset); cnt becomes degree table
  for (int e = gtid; e < EDGES; e += PTHR) {
    const int d = ei[EDGES + e];
    const int s = ei[e];
    const int slot = atomicAdd(&cnt[d], 1);
    if (slot < 64) csr_pad[d * 64 + (slot & 7) * 8 + (slot >> 3)] = s;
  }

  // weight convert+swizzle: one 16x32 tile per wave, exactly NL*128 = 768 waves
  if (gw < NL * 128) {
    const int layer = gw >> 7, rem = gw & 127;
    const int mat = rem >> 5, tile = rem & 31;
    const int nt = tile >> 2, kt = tile & 3;
    const float* W = ((mat == 0) ? Wq : (mat == 1) ? Wk : (mat == 2) ? Wv : Ws)
                     + layer * DH * DH;
    const int nn = nt * 16 + (lane & 15);
    const int k0 = kt * 32 + (lane >> 4) * 8;
    unsigned pk[4];
#pragma unroll
    for (int jj = 0; jj < 4; ++jj) {
      const unsigned lo = f2bf(W[(k0 + 2 * jj) * DH + nn]);
      const unsigned hi = f2bf(W[(k0 + 2 * jj + 1) * DH + nn]);
      pk[jj] = lo | (hi << 16);
    }
    uint4 o = {pk[0], pk[1], pk[2], pk[3]};
    *(uint4*)&Wf[(((layer * 4 + mat) * 32 + tile) * 64 + lane) * 8] = o;
  }

  // input proj: wave per node, lane owns 2 dims
  for (int n = gw; n < NNODES; n += PWAV) {
    const int d0 = lane * 2;
    float xs[9];
#pragma unroll
    for (int f = 0; f < 9; ++f) xs[f] = x[n * 9 + f];
    float a0 = bin[d0], a1 = bin[d0 + 1];
#pragma unroll
    for (int f = 0; f < 9; ++f) {
      const float2 w = *(const float2*)&Win[f * DH + d0];
      a0 = fmaf(xs[f], w.x, a0);
      a1 = fmaf(xs[f], w.y, a1);
    }
    const float2 pev = *(const float2*)&pe[((n / NNPG) % SEQ) * DH + d0];
    const float v0 = a0 + pev.x, v1 = a1 + pev.y;
    float2 hv = {v0, v1};
    *(float2*)&h[n * DH + d0] = hv;
    *(unsigned*)&hb[n * DH + d0] = (unsigned)f2bf(v0) | ((unsigned)f2bf(v1) << 16);
  }
}

// ---------------- layer-0 Q/K/V/skip GEMM (A from hb via swizzled LDS) --------
__global__ __launch_bounds__(512, 2) void k_gemm(const unsigned short* __restrict__ hb,
    const unsigned short* __restrict__ Wf,
    const float* __restrict__ bq, const float* __restrict__ bk,
    const float* __restrict__ bv, const float* __restrict__ bs,
    unsigned short* __restrict__ qb, unsigned char* __restrict__ kv8,
    float* __restrict__ xr) {
  __shared__ uint4 As4[512];                   // 32 rows x 256B, swizzled
  const int mt = blockIdx.x;
  const int wv = threadIdx.x >> 6, lane = threadIdx.x & 63;
  {
    const int t = threadIdx.x;
    const int row = t >> 4, cb = t & 15;
    As4[t] = *(const uint4*)&hb[(mt * 32 + row) * DH + ((cb ^ (row & 7)) * 8)];
  }
  __syncthreads();

  const int cg = wv;                           // col group 0..7 (64 cols each)
  const int mat = cg >> 1, nbase = (cg & 1) * 64;
  const unsigned short* Wm = Wf + mat * 16384;
  const float* bias = (mat == 0) ? bq : (mat == 1) ? bk : (mat == 2) ? bv : bs;
  const int m0 = lane & 15, quad = lane >> 4;
  const int nt0 = (cg & 1) * 4;
  const char* Asb = (const char*)As4;

  const f32x4 z = {0.f, 0.f, 0.f, 0.f};
  f32x4 acc[2][4] = {{z, z, z, z}, {z, z, z, z}};
#pragma unroll
  for (int kt = 0; kt < 4; ++kt) {
    const int cbr = kt * 4 + quad;
    const bf16x8 a0 = *(const bf16x8*)(Asb + m0 * 256 + ((cbr ^ (m0 & 7)) * 16));
    const bf16x8 a1 = *(const bf16x8*)(Asb + (16 + m0) * 256 + ((cbr ^ (m0 & 7)) * 16));
#pragma unroll
    for (int j = 0; j < 4; ++j) {
      const bf16x8 b = *(const bf16x8*)&Wm[(((nt0 + j) * 4 + kt) * 64 + lane) * 8];
      acc[0][j] = __builtin_amdgcn_mfma_f32_16x16x32_bf16(a0, b, acc[0][j], 0, 0, 0);
      acc[1][j] = __builtin_amdgcn_mfma_f32_16x16x32_bf16(a1, b, acc[1][j], 0, 0, 0);
    }
  }
  const int kvoff = (mat == 1) ? 0 : 16;
#pragma unroll
  for (int half = 0; half < 2; ++half) {
#pragma unroll
    for (int j = 0; j < 4; ++j) {
      const int col = nbase + j * 16 + m0;
      const float bvv = bias[col];
#pragma unroll
      for (int r = 0; r < 4; ++r) {
        const float val = acc[half][j][r] + bvv;
        const int row = mt * 32 + half * 16 + quad * 4 + r;
        if (mat == 0) {
          qb[row * DH + col] = f2bf(val);
        } else if (mat == 3) {
          xr[row * DH + col] = val;
        } else {
          const float nbv = __shfl_xor(val, 1);
          if ((lane & 1) == 0) {
            const int pk = __builtin_amdgcn_cvt_pk_fp8_f32(val, nbv, 0, false);
            const int head = col >> 4, dim = col & 15;
            *(unsigned short*)&kv8[row * 256 + head * 32 + kvoff + dim] =
                (unsigned short)pk;
          }
        }
      }
    }
  }
}

// ---------------- attention helpers ----------------
__device__ __forceinline__ void decode16bf2(const uint4 a, const uint4 b, f32x2* r) {
  r[0] = mk2(bfl(a.x), bfh(a.x)); r[1] = mk2(bfl(a.y), bfh(a.y));
  r[2] = mk2(bfl(a.z), bfh(a.z)); r[3] = mk2(bfl(a.w), bfh(a.w));
  r[4] = mk2(bfl(b.x), bfh(b.x)); r[5] = mk2(bfl(b.y), bfh(b.y));
  r[6] = mk2(bfl(b.z), bfh(b.z)); r[7] = mk2(bfl(b.w), bfh(b.w));
}

__device__ __forceinline__ void decode8x2(const uint4 u, f32x2* r) {
  r[0] = __builtin_amdgcn_cvt_pk_f32_fp8(u.x, false);
  r[1] = __builtin_amdgcn_cvt_pk_f32_fp8(u.x, true);
  r[2] = __builtin_amdgcn_cvt_pk_f32_fp8(u.y, false);
  r[3] = __builtin_amdgcn_cvt_pk_f32_fp8(u.y, true);
  r[4] = __builtin_amdgcn_cvt_pk_f32_fp8(u.z, false);
  r[5] = __builtin_amdgcn_cvt_pk_f32_fp8(u.z, true);
  r[6] = __builtin_amdgcn_cvt_pk_f32_fp8(u.w, false);
  r[7] = __builtin_amdgcn_cvt_pk_f32_fp8(u.w, true);
}

__device__ __forceinline__ void edge_acc2(const uint4 ku, const uint4 vu, bool valid,
    const f32x2* __restrict__ q2, f32x2* __restrict__ a2, float& denom) {
  f32x2 kr[8];
  decode8x2(ku, kr);
  f32x2 d2 = mk2(0.f, 0.f);
#pragma unroll
  for (int c = 0; c < 8; ++c) d2 = d2 + q2[c] * kr[c];
  const float dot = d2[0] + d2[1];
  const float ex = valid ? __expf(dot * 0.25f) : 0.f;
  denom += ex;
  f32x2 vr[8];
  decode8x2(vu, vr);
  const f32x2 e2 = mk2(ex, ex);
#pragma unroll
  for (int c = 0; c < 8; ++c) a2[c] = a2[c] + e2 * vr[c];
}

// ---------------- fused layer: attn(l) + epi + [gemm(l+1) | final MLP] --------
// Round-7 structure (32-node tile, proven): 512 blocks x 512 thr, wave does 4
// nodes serially. Software-pipelined node loop — node t+1's control and
// stream loads (csr_pad/deg/q/xr/h) issue during node t's compute, and node
// t's K/V gathers issue at iteration top (addresses prefetched an iteration
// ago). Pure load scheduling; per-node FP order unchanged.
template <bool LAST>
__global__ __launch_bounds__(512, 2) void k_layer(
    const unsigned short* __restrict__ qb_i, const unsigned char* __restrict__ kv8_i,
    const int* __restrict__ degv, const int* __restrict__ csr_pad,
    float* __restrict__ h, const float* __restrict__ xr_i,
    const float* __restrict__ Wb, const float* __restrict__ bb,
    const float* __restrict__ ln_g, const float* __restrict__ ln_b,
    const unsigned short* __restrict__ Wfn, const float* __restrict__ bqn,
    const float* __restrict__ bkn, const float* __restrict__ bvn,
    const float* __restrict__ bsn,
    unsigned short* __restrict__ qb_o, unsigned char* __restrict__ kv8_o,
    float* __restrict__ xr_o,
    const float* __restrict__ Wo1, const float* __restrict__ bo1,
    const float* __restrict__ Wo2, const float* __restrict__ bo2,
    float* __restrict__ out) {
  __shared__ float hsf[32][DH];   // 16KB; !LAST: first 8KB = swizzled bf16 A-tile
  const int wv = threadIdx.x >> 6, lane = threadIdx.x & 63;
  const int nb = blockIdx.x * 32;
  const int es = lane >> 3, hd = lane & 7;   // 8 edge-slots x 8 heads
  const int d0 = hd * CH + es * 2;
  // loop-invariant epilogue operands
  const float2 lw0 = *(const float2*)&Wb[d0];
  const float2 lw1 = *(const float2*)&Wb[DH + d0];
  const float2 lw2 = *(const float2*)&Wb[2 * DH + d0];
  const float2 lg = *(const float2*)&ln_g[d0];
  const float2 lb = *(const float2*)&ln_b[d0];
  const float bbv = bb[0];

  // ---- prefetch node 0's control + stream data
  const int n0 = nb + wv * 4;
  int4 iv = *(const int4*)&csr_pad[n0 * 64 + es * 8];
  int deg = degv[n0];
  const uint4* qp0 = (const uint4*)&qb_i[n0 * DH + hd * CH];
  uint4 qa = qp0[0], qc = qp0[1];
  float2 xrv = *(const float2*)&xr_i[n0 * DH + d0];
  float2 hv = *(const float2*)&h[n0 * DH + d0];

#pragma unroll
  for (int t4 = 0; t4 < 4; ++t4) {
    const int row = wv * 4 + t4;
    const int n = nb + row;
    // ---- issue this node's K/V gathers first (addresses already in regs)
    int ntb = (deg + 7) >> 3;
    if (ntb > 8) ntb = 8;
    const int idx[4] = {iv.x, iv.y, iv.z, iv.w};
    bool valv[4];
#pragma unroll
    for (int t = 0; t < 4; ++t) valv[t] = (es + 8 * t) < deg;
    uint4 kf[4], vf[4];
#pragma unroll
    for (int t = 0; t < 4; ++t) {
      if (t < ntb) {                        // uniform skip of empty batches
        const int s = valv[t] ? idx[t] : 0; // garbage-safe clamp
        const unsigned char* base = &kv8_i[s * 256 + hd * 32];
        kf[t] = *(const uint4*)base;        // K: bytes 0..15 of this head
        vf[t] = *(const uint4*)(base + 16); // V: bytes 16..31 (same 64B line)
      }
    }
    // ---- prefetch next node's control + stream data (overlaps compute below)
    int4 iv_n = iv;
    int deg_n = deg;
    uint4 qa_n = qa, qc_n = qc;
    float2 xrv_n = xrv, hv_n = hv;
    if (t4 < 3) {
      const int nn = n + 1;
      iv_n = *(const int4*)&csr_pad[nn * 64 + es * 8];
      deg_n = degv[nn];
      const uint4* qp = (const uint4*)&qb_i[nn * DH + hd * CH];
      qa_n = qp[0];
      qc_n = qp[1];
      xrv_n = *(const float2*)&xr_i[nn * DH + d0];
      hv_n = *(const float2*)&h[nn * DH + d0];
    }
    // ---- compute (unchanged FP order)
    f32x2 q2[8];
    decode16bf2(qa, qc, q2);
    f32x2 a2[8];
#pragma unroll
    for (int c = 0; c < 8; ++c) a2[c] = mk2(0.f, 0.f);
    float denom = 0.f;
#pragma unroll
    for (int t = 0; t < 4; ++t) {
      if (t < ntb) edge_acc2(kf[t], vf[t], valv[t], q2, a2, denom);
    }
    for (int t = 4; t < ntb; ++t) {  // rare tail (deg > 32): slots 32..63
      const bool v = (es + 8 * t) < deg;
      const int s = v ? csr_pad[n * 64 + es * 8 + t] : 0;
      const unsigned char* base = &kv8_i[s * 256 + hd * 32];
      const uint4 ku = *(const uint4*)base;
      const uint4 vu = *(const uint4*)(base + 16);
      edge_acc2(ku, vu, v, q2, a2, denom);
    }
#pragma unroll
    for (int off = 8; off <= 32; off <<= 1) denom += __shfl_xor(denom, off);
    // reduce-scatter across edge-slots; lane keeps only its own pair (c = es)
    const bool hi32 = (lane & 32) != 0;
    f32x2 r4[4];
#pragma unroll
    for (int c = 0; c < 4; ++c) {
      const f32x2 keep = hi32 ? a2[c + 4] : a2[c];
      const f32x2 send = hi32 ? a2[c] : a2[c + 4];
      const f32x2 rec = mk2(__shfl_xor(send[0], 32), __shfl_xor(send[1], 32));
      r4[c] = keep + rec;
    }
    const bool hi16 = (lane & 16) != 0;
    f32x2 r2[2];
#pragma unroll
    for (int c = 0; c < 2; ++c) {
      const f32x2 keep = hi16 ? r4[c + 2] : r4[c];
      const f32x2 send = hi16 ? r4[c] : r4[c + 2];
      const f32x2 rec = mk2(__shfl_xor(send[0], 16), __shfl_xor(send[1], 16));
      r2[c] = keep + rec;
    }
    const bool hi8 = (lane & 8) != 0;
    f32x2 rr;
    {
      const f32x2 keep = hi8 ? r2[1] : r2[0];
      const f32x2 send = hi8 ? r2[0] : r2[1];
      const f32x2 rec = mk2(__shfl_xor(send[0], 8), __shfl_xor(send[1], 8));
      rr = keep + rec;
    }
    const float inv = 1.f / (denom + 1e-16f);
    const float ax = rr[0] * inv, ay = rr[1] * inv;
    float p = ax * lw0.x + ay * lw0.y + xrv.x * lw1.x + xrv.y * lw1.y
            + (ax - xrv.x) * lw2.x + (ay - xrv.y) * lw2.y;
#pragma unroll
    for (int off = 1; off <= 32; off <<= 1) p += __shfl_xor(p, off);
    const float beta = 1.f / (1.f + __expf(-(p + bbv)));
    const float t0 = hv.x + beta * xrv.x + (1.f - beta) * ax;
    const float t1 = hv.y + beta * xrv.y + (1.f - beta) * ay;
    float sum = t0 + t1, sq = t0 * t0 + t1 * t1;
#pragma unroll
    for (int off = 1; off <= 32; off <<= 1) {
      sum += __shfl_xor(sum, off);
      sq  += __shfl_xor(sq, off);
    }
    const float mu = sum * (1.f / DH);
    const float rinv = rsqrtf(sq * (1.f / DH) - mu * mu + 1e-5f);
    const float2 o = {(t0 - mu) * rinv * lg.x + lb.x, (t1 - mu) * rinv * lg.y + lb.y};
    if constexpr (!LAST) {
      *(float2*)&h[n * DH + d0] = o;
      // next-layer A-tile: bf16 pair -> swizzled LDS (2-way banks = free)
      const int cb = 2 * hd + (es >> 2);     // linear 16B-block index of d0
      *(unsigned*)((char*)hsf + row * 256 + ((cb ^ (row & 7)) * 16) + (es & 3) * 4) =
          (unsigned)f2bf(o.x) | ((unsigned)f2bf(o.y) << 16);
    } else {
      hsf[row][d0] = o.x;
      hsf[row][d0 + 1] = o.y;
    }
    // ---- rotate prefetched data in (static, unrolled)
    iv = iv_n; deg = deg_n; qa = qa_n; qc = qc_n; xrv = xrv_n; hv = hv_n;
  }
  __syncthreads();

  if constexpr (!LAST) {
    // ---- gemm(l+1) for rows nb..nb+31, A from LDS
    const int cg = wv;
    const int mat = cg >> 1, nbase = (cg & 1) * 64;
    const unsigned short* Wm = Wfn + mat * 16384;
    const float* bias = (mat == 0) ? bqn : (mat == 1) ? bkn : (mat == 2) ? bvn : bsn;
    const int m0 = lane & 15, quad = lane >> 4;
    const int nt0 = (cg & 1) * 4;
    const char* Asb = (const char*)hsf;
    const f32x4 z = {0.f, 0.f, 0.f, 0.f};
    f32x4 acc[2][4] = {{z, z, z, z}, {z, z, z, z}};
#pragma unroll
    for (int kt = 0; kt < 4; ++kt) {
      const int cbr = kt * 4 + quad;
      const bf16x8 a0 = *(const bf16x8*)(Asb + m0 * 256 + ((cbr ^ (m0 & 7)) * 16));
      const bf16x8 a1 = *(const bf16x8*)(Asb + (16 + m0) * 256 + ((cbr ^ (m0 & 7)) * 16));
#pragma unroll
      for (int j = 0; j < 4; ++j) {
        const bf16x8 b = *(const bf16x8*)&Wm[(((nt0 + j) * 4 + kt) * 64 + lane) * 8];
        acc[0][j] = __builtin_amdgcn_mfma_f32_16x16x32_bf16(a0, b, acc[0][j], 0, 0, 0);
        acc[1][j] = __builtin_amdgcn_mfma_f32_16x16x32_bf16(a1, b, acc[1][j], 0, 0, 0);
      }
    }
    const int kvoff = (mat == 1) ? 0 : 16;
#pragma unroll
    for (int half = 0; half < 2; ++half) {
#pragma unroll
      for (int j = 0; j < 4; ++j) {
        const int col = nbase + j * 16 + m0;
        const float bvv = bias[col];
#pragma unroll
        for (int r = 0; r < 4; ++r) {
          const float val = acc[half][j][r] + bvv;
          const int row = nb + half * 16 + quad * 4 + r;
          if (mat == 0) {
            qb_o[row * DH + col] = f2bf(val);
          } else if (mat == 3) {
            xr_o[row * DH + col] = val;
          } else {
            const float nbv = __shfl_xor(val, 1);
            if ((lane & 1) == 0) {
              const int pk = __builtin_amdgcn_cvt_pk_fp8_f32(val, nbv, 0, false);
              const int head = col >> 4, dim = col & 15;
              *(unsigned short*)&kv8_o[row * 256 + head * 32 + kvoff + dim] =
                  (unsigned short)pk;
            }
          }
        }
      }
    }
  } else {
    // ---- final MLP: relu(h@Wo1+bo1)@Wo2+bo2; wave loops its 4 nodes
    for (int t4 = 0; t4 < 4; ++t4) {
      const int row = wv * 4 + t4;
      const int n = nb + row;
      float m = bo1[lane];
#pragma unroll 16
      for (int d = 0; d < DH; ++d) m = fmaf(hsf[row][d], Wo1[d * 64 + lane], m);
      m = fmaxf(m, 0.f);
      float o0 = m * Wo2[lane * 3 + 0];
      float o1 = m * Wo2[lane * 3 + 1];
      float o2 = m * Wo2[lane * 3 + 2];
#pragma unroll
      for (int off = 32; off; off >>= 1) {
        o0 += __shfl_xor(o0, off);
        o1 += __shfl_xor(o1, off);
        o2 += __shfl_xor(o2, off);
      }
      if (lane == 0) {
        out[n * 3 + 0] = o0 + bo2[0];
        out[n * 3 + 1] = o1 + bo2[1];
        out[n * 3 + 2] = o2 + bo2[2];
      }
    }
  }
}

extern "C" void kernel_launch(void* const* d_in, const int* in_sizes, int n_in,
                              void* d_out, int out_size, void* d_ws, size_t ws_size,
                              hipStream_t stream) {
  const float* x   = (const float*)d_in[0];
  const int*   ei  = (const int*)d_in[1];
  const float* pe  = (const float*)d_in[2];
  const float* Win = (const float*)d_in[3];
  const float* bin = (const float*)d_in[4];
  const float* Wq  = (const float*)d_in[5];
  const float* bq  = (const float*)d_in[6];
  const float* Wk  = (const float*)d_in[7];
  const float* bk  = (const float*)d_in[8];
  const float* Wv  = (const float*)d_in[9];
  const float* bv  = (const float*)d_in[10];
  const float* Wsk = (const float*)d_in[11];
  const float* bs  = (const float*)d_in[12];
  const float* Wb  = (const float*)d_in[13];
  const float* bb  = (const float*)d_in[14];
  const float* lng = (const float*)d_in[15];
  const float* lnb = (const float*)d_in[16];
  const float* Wo1 = (const float*)d_in[17];
  const float* bo1 = (const float*)d_in[18];
  const float* Wo2 = (const float*)d_in[19];
  const float* bo2 = (const float*)d_in[20];

  const size_t NU = (size_t)NNODES * DH;
  char* base = (char*)d_ws;
  float* h   = (float*)base;                  base += NU * 4;
  unsigned short* hb = (unsigned short*)base; base += NU * 2;
  unsigned short* Wf = (unsigned short*)base; base += (size_t)NL * 4 * 16384 * 2;
  int* cnt     = (int*)base;                  base += NNODES * 4;     // degree table
  int* csr_pad = (int*)base;                  base += (size_t)NNODES * 64 * 4;
  // ping-pong per-layer buffers (WAR-free fused gemm)
  float* xrA = (float*)base;                  base += NU * 4;
  float* xrB = (float*)base;                  base += NU * 4;
  unsigned short* qbA = (unsigned short*)base; base += NU * 2;
  unsigned short* qbB = (unsigned short*)base; base += NU * 2;
  unsigned char* kvA = (unsigned char*)base;  base += NU * 2;
  unsigned char* kvB = (unsigned char*)base;  base += NU * 2;

  (void)hipMemsetAsync(cnt, 0, NNODES * sizeof(int), stream);
  k_pro<<<PBLK, 256, 0, stream>>>(ei, cnt, csr_pad, Wq, Wk, Wv, Wsk, Wf,
                                  x, Win, bin, pe, h, hb);
  k_gemm<<<NNODES / 32, 512, 0, stream>>>(hb, Wf, bq, bk, bv, bs, qbA, kvA, xrA);
  for (int l = 0; l < NL - 1; ++l) {
    const bool even = (l & 1) == 0;
    k_layer<false><<<NNODES / 32, 512, 0, stream>>>(
        even ? qbA : qbB, even ? kvA : kvB, cnt, csr_pad, h, even ? xrA : xrB,
        Wb + l * 3 * DH, bb + l, lng + l * DH, lnb + l * DH,
        Wf + (size_t)(l + 1) * 4 * 16384,
        bq + (l + 1) * DH, bk + (l + 1) * DH, bv + (l + 1) * DH, bs + (l + 1) * DH,
        even ? qbB : qbA, even ? kvB : kvA, even ? xrB : xrA,
        Wo1, bo1, Wo2, bo2, (float*)d_out);
  }
  // l = 5 is odd -> reads B set
  k_layer<true><<<NNODES / 32, 512, 0, stream>>>(
      qbB, kvB, cnt, csr_pad, h, xrB,
      Wb + 5 * 3 * DH, bb + 5, lng + 5 * DH, lnb + 5 * DH,
      Wf, bq, bk, bv, bs, qbA, kvA, xrA,
      Wo1, bo1, Wo2, bo2, (float*)d_out);
}